// Round 3
// baseline (602.862 us; speedup 1.0000x reference)
//
#include <hip/hip_runtime.h>
#include <hip/hip_bf16.h>
#include <stdint.h>

#define NB 2
#define SEQ 1024
#define DMODEL 768
#define NH 12
#define DH 64
#define SCALE 0.125f

typedef __hip_bfloat16 bf16;

__device__ __forceinline__ float b2f(bf16 x){ return __bfloat162float(x); }
__device__ __forceinline__ bf16 f2b(float x){ return __float2bfloat16(x); }

// ---------------- LayerNorm: x[2048,768] f32 -> xn f32 ----------------
__global__ __launch_bounds__(256) void ln_kernel(const float* __restrict__ x,
                                                 const float* __restrict__ g,
                                                 const float* __restrict__ bta,
                                                 float* __restrict__ xn){
  int row = blockIdx.x; int t = threadIdx.x;
  const float* xr = x + (size_t)row*DMODEL;
  float v0[3]; float s = 0.f, s2 = 0.f;
  #pragma unroll
  for (int i=0;i<3;i++){ float val = xr[t+256*i]; v0[i]=val; s+=val; s2+=val*val; }
  __shared__ float sb[256], s2b[256];
  sb[t]=s; s2b[t]=s2; __syncthreads();
  for (int off=128; off>0; off>>=1){
    if (t<off){ sb[t]+=sb[t+off]; s2b[t]+=s2b[t+off]; }
    __syncthreads();
  }
  float mean = sb[0]*(1.f/DMODEL);
  float var  = s2b[0]*(1.f/DMODEL) - mean*mean;
  float rstd = rsqrtf(var + 1e-5f);
  #pragma unroll
  for (int i=0;i<3;i++){
    int c = t+256*i;
    xn[(size_t)row*DMODEL + c] = (v0[i]-mean)*rstd*g[c] + bta[c];
  }
}

// ---------------- QKV GEMM: xn[2048,768] @ w_qkv^T[768,2304] ----------------
__global__ __launch_bounds__(256) void gemm_qkv(const float* __restrict__ A,
                                                const float* __restrict__ W,
                                                float* __restrict__ q,
                                                float* __restrict__ k,
                                                float* __restrict__ v){
  __shared__ float As[16][68];
  __shared__ float Bs[16][68];
  int n0 = blockIdx.x*64, m0 = blockIdx.y*64;
  int t = threadIdx.x; int tn = t&15, tm = t>>4;
  float acc[4][4] = {};
  for (int k0=0;k0<768;k0+=16){
    #pragma unroll
    for (int i=0;i<4;i++){ int idx = t + i*256; int kk2 = idx&15, mm = idx>>4;
      As[kk2][mm] = A[(size_t)(m0+mm)*768 + k0 + kk2]; }
    #pragma unroll
    for (int i=0;i<4;i++){ int idx = t + i*256; int kk2 = idx&15, nn = idx>>4;
      Bs[kk2][nn] = W[(size_t)(n0+nn)*768 + k0 + kk2]; }
    __syncthreads();
    #pragma unroll
    for (int kk2=0;kk2<16;kk2++){
      float a[4], bb[4];
      #pragma unroll
      for (int i=0;i<4;i++) a[i] = As[kk2][tm*4+i];
      #pragma unroll
      for (int j=0;j<4;j++) bb[j] = Bs[kk2][tn*4+j];
      #pragma unroll
      for (int i=0;i<4;i++)
        #pragma unroll
        for (int j=0;j<4;j++) acc[i][j] += a[i]*bb[j];
    }
    __syncthreads();
  }
  #pragma unroll
  for (int i=0;i<4;i++){
    int m = m0 + tm*4 + i; int bb2 = m>>10, n = m&1023;
    #pragma unroll
    for (int j=0;j<4;j++){
      int c = n0 + tn*4 + j; int which = c/768; int rem = c - which*768;
      int h = rem>>6, dd = rem&63;
      float val = acc[i][j];
      float* dst = (which==0)? q : ((which==1)? k : v);
      if (which==0) val *= SCALE;
      dst[(size_t)((bb2*NH + h)*SEQ + n)*DH + dd] = val;
    }
  }
}

// ---------------- scores + softmax for ONE b: 8 rows/block -> attn bf16 [12,1024,1024] ----------------
__global__ __launch_bounds__(256) void attn_kernel(const float* __restrict__ qB,
                                                   const float* __restrict__ kB,
                                                   bf16* __restrict__ attnB){
  int h = blockIdx.y; int r0 = blockIdx.x*8;
  const float* qb = qB + (size_t)h*SEQ*DH;
  const float* kb = kB + (size_t)h*SEQ*DH;
  __shared__ float qs[8][64];
  __shared__ float ks[64][65];
  __shared__ float s[8][1024];
  __shared__ float red[8][32];
  __shared__ float invs[8];
  int t = threadIdx.x;
  { int rr = t>>6, dd = t&63;
    qs[rr][dd]   = qb[(size_t)(r0+rr)*64+dd];
    qs[rr+4][dd] = qb[(size_t)(r0+rr+4)*64+dd]; }
  for (int mt=0; mt<1024; mt+=64){
    __syncthreads();
    #pragma unroll
    for (int i=0;i<16;i++){ int idx = t + 256*i; int m = idx>>6, dd = idx&63;
      ks[m][dd] = kb[(size_t)(mt+m)*64+dd]; }
    __syncthreads();
    int m = t&63; int rb = t>>6;
    #pragma unroll
    for (int rr2=0; rr2<2; rr2++){
      int r = rb + rr2*4;
      float acc = 0.f;
      #pragma unroll
      for (int dd=0; dd<64; dd++) acc += qs[r][dd]*ks[m][dd];
      s[r][mt+m] = acc;
    }
  }
  __syncthreads();
  int r = t>>5, lane = t&31;
  float mx = -3e38f;
  for (int i=lane;i<1024;i+=32) mx = fmaxf(mx, s[r][i]);
  red[r][lane] = mx; __syncthreads();
  float rmx = red[r][0];
  #pragma unroll
  for (int i=1;i<32;i++) rmx = fmaxf(rmx, red[r][i]);
  __syncthreads();
  float sum = 0.f;
  for (int i=lane;i<1024;i+=32){ float e = __expf(s[r][i]-rmx); s[r][i]=e; sum+=e; }
  red[r][lane] = sum; __syncthreads();
  float rsum = 0.f;
  #pragma unroll
  for (int i=0;i<32;i++) rsum += red[r][i];
  if (lane==0) invs[r] = 1.0f/rsum;
  __syncthreads();
  bf16* arow = attnB + ((size_t)h*SEQ + r0)*1024;
  for (int idx=t; idx<8192; idx+=256){
    int rr2 = idx>>10, m2 = idx&1023;
    arow[(size_t)rr2*1024 + m2] = f2b(s[rr2][m2]*invs[rr2]);
  }
}

// ---------------- M = (-0.5*theta) @ gnn_w  (Tw+Tw^T == -1 identically) ----------------
__global__ __launch_bounds__(256) void mmat_kernel(const float* __restrict__ theta,
                                                   const float* __restrict__ gnn,
                                                   float* __restrict__ Mm){
  int t = threadIdx.x;
  if (t < 144){
    int i = t/12, kx = t%12;
    float sacc = 0.f;
    for (int j=0;j<12;j++) sacc += (-0.5f)*theta[i*12+j] * gnn[j*12+kx];
    Mm[t] = sacc;
  }
}

// ---------------- in-place head mix for ONE b: attn <- attn + relu(M @ attn) ----------------
__global__ __launch_bounds__(256) void mix_kernel(bf16* __restrict__ attnB,
                                                  const float* __restrict__ Mm){
  __shared__ float Ms[144];
  int t = threadIdx.x;
  if (t<144) Ms[t] = Mm[t];
  __syncthreads();
  size_t nm = (size_t)blockIdx.x*256 + t;        // 0 .. 1024*1024-1
  float a[12], c[12];
  #pragma unroll
  for (int hh=0;hh<12;hh++) a[hh] = b2f(attnB[nm + (size_t)hh*1048576]);
  #pragma unroll
  for (int i=0;i<12;i++){
    float sby = 0.f;
    #pragma unroll
    for (int j=0;j<12;j++) sby += Ms[i*12+j]*a[j];
    c[i] = a[i] + fmaxf(sby, 0.f);
  }
  #pragma unroll
  for (int hh=0;hh<12;hh++) attnB[nm + (size_t)hh*1048576] = f2b(c[hh]);
}

// ---------------- PV GEMM for ONE b, per h: comb[1024,1024] @ v[1024,64] -> aout[n, h*64+d] ----------------
__global__ __launch_bounds__(256) void pv_gemm(const bf16* __restrict__ combB,
                                               const float* __restrict__ vB,
                                               float* __restrict__ aoutB){
  int h = blockIdx.y; int m0 = blockIdx.x*64;
  const bf16* A  = combB + (size_t)h*SEQ*1024;
  const float* Bv = vB   + (size_t)h*SEQ*DH;
  __shared__ float As[16][68];
  __shared__ float Bs[16][68];
  int t = threadIdx.x; int tn = t&15, tm = t>>4;
  float acc[4][4] = {};
  for (int k0=0;k0<1024;k0+=16){
    #pragma unroll
    for (int i=0;i<4;i++){ int idx = t+i*256; int kk2 = idx&15, mm = idx>>4;
      As[kk2][mm] = b2f(A[(size_t)(m0+mm)*1024 + k0+kk2]); }
    #pragma unroll
    for (int i=0;i<4;i++){ int idx = t+i*256; int kk2 = idx>>6, nn = idx&63;
      Bs[kk2][nn] = Bv[(size_t)(k0+kk2)*64 + nn]; }
    __syncthreads();
    #pragma unroll
    for (int kk2=0;kk2<16;kk2++){
      float a[4], bb[4];
      #pragma unroll
      for (int i=0;i<4;i++) a[i] = As[kk2][tm*4+i];
      #pragma unroll
      for (int j=0;j<4;j++) bb[j] = Bs[kk2][tn*4+j];
      #pragma unroll
      for (int i=0;i<4;i++)
        #pragma unroll
        for (int j=0;j<4;j++) acc[i][j] += a[i]*bb[j];
    }
    __syncthreads();
  }
  #pragma unroll
  for (int i=0;i<4;i++){
    int n = m0 + tm*4 + i;
    #pragma unroll
    for (int j=0;j<4;j++){
      int dd = tn*4 + j;
      aoutB[(size_t)n*DMODEL + h*DH + dd] = acc[i][j];
    }
  }
}

// ---------------- out proj: aout[2048,768] @ w_out^T[768,768] + b_out -> f32 out ----------------
__global__ __launch_bounds__(256) void gemm_out(const float* __restrict__ A,
                                                const float* __restrict__ W,
                                                const float* __restrict__ bias,
                                                float* __restrict__ out){
  __shared__ float As[16][68];
  __shared__ float Bs[16][68];
  int n0 = blockIdx.x*64, m0 = blockIdx.y*64;
  int t = threadIdx.x; int tn = t&15, tm = t>>4;
  float acc[4][4] = {};
  for (int k0=0;k0<768;k0+=16){
    #pragma unroll
    for (int i=0;i<4;i++){ int idx = t + i*256; int kk2 = idx&15, mm = idx>>4;
      As[kk2][mm] = A[(size_t)(m0+mm)*768 + k0 + kk2]; }
    #pragma unroll
    for (int i=0;i<4;i++){ int idx = t + i*256; int kk2 = idx&15, nn = idx>>4;
      Bs[kk2][nn] = W[(size_t)(n0+nn)*768 + k0 + kk2]; }
    __syncthreads();
    #pragma unroll
    for (int kk2=0;kk2<16;kk2++){
      float a[4], bb[4];
      #pragma unroll
      for (int i=0;i<4;i++) a[i] = As[kk2][tm*4+i];
      #pragma unroll
      for (int j=0;j<4;j++) bb[j] = Bs[kk2][tn*4+j];
      #pragma unroll
      for (int i=0;i<4;i++)
        #pragma unroll
        for (int j=0;j<4;j++) acc[i][j] += a[i]*bb[j];
    }
    __syncthreads();
  }
  #pragma unroll
  for (int i=0;i<4;i++){
    int m = m0 + tm*4 + i;
    #pragma unroll
    for (int j=0;j<4;j++){
      int c = n0 + tn*4 + j;
      out[(size_t)m*768 + c] = acc[i][j] + bias[c];
    }
  }
}

extern "C" void kernel_launch(void* const* d_in, const int* in_sizes, int n_in,
                              void* d_out, int out_size, void* d_ws, size_t ws_size,
                              hipStream_t stream){
  const float* x     = (const float*)d_in[0];
  const float* ln_g  = (const float*)d_in[1];
  const float* ln_b  = (const float*)d_in[2];
  const float* w_qkv = (const float*)d_in[3];
  const float* w_out = (const float*)d_in[4];
  const float* b_out = (const float*)d_in[5];
  const float* theta = (const float*)d_in[6];
  const float* gnn   = (const float*)d_in[7];
  float* out = (float*)d_out;

  const size_t T = (size_t)NB*SEQ*DMODEL;        // 1,572,864
  float* ws   = (float*)d_ws;
  float* xn   = ws;                               // [0, T)   — dead after gemm_qkv
  float* aout = ws;                               // aliases xn (written by pv later)
  float* q    = ws + T;                           // [T, 2T)
  float* k    = q + T;                            // [2T, 3T)
  float* v    = k + T;                            // [3T, 4T)
  float* Mm   = v + T;                            // [4T, 4T+256)
  bf16*  attn = (bf16*)(Mm + 256);                // 12*1024*1024 bf16 = 25.2 MB (one b)
  // total ws: ~48 MB

  ln_kernel<<<dim3(NB*SEQ), dim3(256), 0, stream>>>(x, ln_g, ln_b, xn);
  gemm_qkv<<<dim3(36, 32), dim3(256), 0, stream>>>(xn, w_qkv, q, k, v);
  mmat_kernel<<<dim3(1), dim3(256), 0, stream>>>(theta, gnn, Mm);

  for (int b=0; b<NB; b++){
    const float* qB = q + (size_t)b*NH*SEQ*DH;
    const float* kB = k + (size_t)b*NH*SEQ*DH;
    const float* vB = v + (size_t)b*NH*SEQ*DH;
    float* aoutB = aout + (size_t)b*SEQ*DMODEL;
    attn_kernel<<<dim3(128, NH), dim3(256), 0, stream>>>(qB, kB, attn);
    mix_kernel<<<dim3(4096), dim3(256), 0, stream>>>(attn, Mm);
    pv_gemm<<<dim3(16, NH), dim3(256), 0, stream>>>(attn, vB, aoutB);
  }

  gemm_out<<<dim3(12, 32), dim3(256), 0, stream>>>(aout, w_out, b_out, out);
}

// Round 4
// 290.920 us; speedup vs baseline: 2.0723x; 2.0723x over previous
//
#include <hip/hip_runtime.h>
#include <hip/hip_bf16.h>
#include <stdint.h>

#define NB 2
#define SEQ 1024
#define DMODEL 768
#define NH 12
#define DH 64
#define SCALE 0.125f

typedef __hip_bfloat16 bf16;
typedef __attribute__((ext_vector_type(8))) short short8;   // 8 x bf16 = 4 VGPRs
typedef __attribute__((ext_vector_type(4))) float f32x4;    // MFMA C/D

__device__ __forceinline__ float b2f(bf16 x){ return __bfloat162float(x); }
__device__ __forceinline__ bf16 f2b(float x){ return __float2bfloat16(x); }
__device__ __forceinline__ unsigned short f2bu(float x){
  bf16 h = __float2bfloat16(x); return *reinterpret_cast<unsigned short*>(&h);
}
__device__ __forceinline__ float u2f(unsigned short u){
  return __uint_as_float(((unsigned)u) << 16);
}

// ---------------- f32 -> bf16 convert ----------------
__global__ __launch_bounds__(256) void cvt_kernel(const float* __restrict__ src,
                                                  bf16* __restrict__ dst, int n){
  int i = blockIdx.x*256 + threadIdx.x;
  if (i < n) dst[i] = f2b(src[i]);
}

// ---------------- LayerNorm: x[2048,768] f32 -> xn bf16 ----------------
__global__ __launch_bounds__(256) void ln_kernel(const float* __restrict__ x,
                                                 const float* __restrict__ g,
                                                 const float* __restrict__ bta,
                                                 bf16* __restrict__ xn){
  int row = blockIdx.x; int t = threadIdx.x;
  const float* xr = x + (size_t)row*DMODEL;
  float v0[3]; float s = 0.f, s2 = 0.f;
  #pragma unroll
  for (int i=0;i<3;i++){ float val = xr[t+256*i]; v0[i]=val; s+=val; s2+=val*val; }
  __shared__ float sb[256], s2b[256];
  sb[t]=s; s2b[t]=s2; __syncthreads();
  for (int off=128; off>0; off>>=1){
    if (t<off){ sb[t]+=sb[t+off]; s2b[t]+=s2b[t+off]; }
    __syncthreads();
  }
  float mean = sb[0]*(1.f/DMODEL);
  float var  = s2b[0]*(1.f/DMODEL) - mean*mean;
  float rstd = rsqrtf(var + 1e-5f);
  #pragma unroll
  for (int i=0;i<3;i++){
    int c = t+256*i;
    xn[(size_t)row*DMODEL + c] = f2b((v0[i]-mean)*rstd*g[c] + bta[c]);
  }
}

// ---------------- QKV GEMM (MFMA): xn[2048,768] @ wqkv^T -> q,k bf16 [b,h,n,d]; v -> vt [b,h,d,n] ----------------
__global__ __launch_bounds__(256) void gemm_qkv(const bf16* __restrict__ A,
                                                const bf16* __restrict__ W,
                                                bf16* __restrict__ q,
                                                bf16* __restrict__ k,
                                                bf16* __restrict__ vt){
  __shared__ bf16 As[128*32];
  __shared__ bf16 Bs[128*32];
  int n0 = blockIdx.x*128, m0 = blockIdx.y*128;
  int t = threadIdx.x, w = t>>6, lane = t&63;
  int ln16 = lane&15, q8 = (lane>>4)*8;
  int wm = w>>1, wn = w&1;
  f32x4 acc[4][4] = {};
  for (int k0=0; k0<768; k0+=32){
    __syncthreads();
    #pragma unroll
    for (int i=0;i<2;i++){
      int cc = t + i*256;               // 512 chunks of 16B each for A and B
      int r = cc>>2, ko = (cc&3)*8;
      *(short8*)&As[r*32+ko] = *(const short8*)&A[(size_t)(m0+r)*768 + k0+ko];
      *(short8*)&Bs[r*32+ko] = *(const short8*)&W[(size_t)(n0+r)*768 + k0+ko];
    }
    __syncthreads();
    short8 af[4], bfr[4];
    #pragma unroll
    for (int mi=0;mi<4;mi++) af[mi]  = *(const short8*)&As[(wm*64+mi*16+ln16)*32 + q8];
    #pragma unroll
    for (int ni=0;ni<4;ni++) bfr[ni] = *(const short8*)&Bs[(wn*64+ni*16+ln16)*32 + q8];
    #pragma unroll
    for (int mi=0;mi<4;mi++)
      #pragma unroll
      for (int ni=0;ni<4;ni++)
        acc[mi][ni] = __builtin_amdgcn_mfma_f32_16x16x32_bf16(af[mi], bfr[ni], acc[mi][ni], 0, 0, 0);
  }
  int quad4 = (lane>>4)*4;
  #pragma unroll
  for (int mi=0;mi<4;mi++){
    #pragma unroll
    for (int ni=0;ni<4;ni++){
      int cg = n0 + wn*64 + ni*16 + ln16;
      int which = cg/768; int rem = cg - which*768;
      int h = rem>>6, dd = rem&63;
      #pragma unroll
      for (int r=0;r<4;r++){
        int m = m0 + wm*64 + mi*16 + quad4 + r;
        int bb = m>>10, n = m&1023;
        float val = acc[mi][ni][r];
        if (which==0)      q [((size_t)(bb*NH+h)*SEQ + n)*DH + dd] = f2b(val*SCALE);
        else if (which==1) k [((size_t)(bb*NH+h)*SEQ + n)*DH + dd] = f2b(val);
        else               vt[((size_t)(bb*NH+h)*DH + dd)*SEQ + n] = f2b(val);
      }
    }
  }
}

// ---------------- QK^T (MFMA) + softmax, 16 rows/block, one batch -> attn bf16 [12,1024,1024] ----------------
__global__ __launch_bounds__(256) void attn_kernel(const bf16* __restrict__ qB,
                                                   const bf16* __restrict__ kB,
                                                   bf16* __restrict__ attnB){
  __shared__ float Sc[16*1028];
  __shared__ float invs[16];
  int h = blockIdx.y; int r0 = blockIdx.x*16;
  int t = threadIdx.x, w = t>>6, lane = t&63;
  int ln16 = lane&15, q8 = (lane>>4)*8;
  // A fragments (q rows), reused for all col tiles
  const bf16* qrow = qB + ((size_t)h*SEQ + r0 + ln16)*DH;
  short8 aq0 = *(const short8*)(qrow + q8);
  short8 aq1 = *(const short8*)(qrow + 32 + q8);
  int quad4 = (lane>>4)*4;
  // wave w handles cols [w*256, w*256+256)
  #pragma unroll 4
  for (int i=0;i<16;i++){
    int c0 = w*256 + i*16;
    const bf16* krow = kB + ((size_t)h*SEQ + c0 + ln16)*DH;
    short8 bk0 = *(const short8*)(krow + q8);
    short8 bk1 = *(const short8*)(krow + 32 + q8);
    f32x4 a = {0.f,0.f,0.f,0.f};
    a = __builtin_amdgcn_mfma_f32_16x16x32_bf16(aq0, bk0, a, 0, 0, 0);
    a = __builtin_amdgcn_mfma_f32_16x16x32_bf16(aq1, bk1, a, 0, 0, 0);
    #pragma unroll
    for (int r=0;r<4;r++) Sc[(quad4+r)*1028 + c0 + ln16] = a[r];
  }
  __syncthreads();
  // softmax: 16 threads per row
  int row = t>>4, sub = t&15;
  float* srow = Sc + row*1028;
  float mx = -3e38f;
  for (int i=sub;i<1024;i+=16) mx = fmaxf(mx, srow[i]);
  #pragma unroll
  for (int msk=1; msk<16; msk<<=1) mx = fmaxf(mx, __shfl_xor(mx, msk));
  float sum = 0.f;
  for (int i=sub;i<1024;i+=16){ float e = __expf(srow[i]-mx); srow[i]=e; sum+=e; }
  #pragma unroll
  for (int msk=1; msk<16; msk<<=1) sum += __shfl_xor(sum, msk);
  if (sub==0) invs[row] = 1.0f/sum;
  __syncthreads();
  bf16* arow = attnB + ((size_t)h*SEQ + r0)*1024;
  for (int idx=t; idx<16384; idx+=256){
    int rr = idx>>10, cc = idx&1023;
    arow[(size_t)rr*1024 + cc] = f2b(Sc[rr*1028+cc]*invs[rr]);
  }
}

// ---------------- M = (-0.5*theta) @ gnn_w  (Tw+Tw^T == -1 identically) ----------------
__global__ __launch_bounds__(256) void mmat_kernel(const float* __restrict__ theta,
                                                   const float* __restrict__ gnn,
                                                   float* __restrict__ Mm){
  int t = threadIdx.x;
  if (t < 144){
    int i = t/12, kx = t%12;
    float sacc = 0.f;
    for (int j=0;j<12;j++) sacc += (-0.5f)*theta[i*12+j] * gnn[j*12+kx];
    Mm[t] = sacc;
  }
}

// ---------------- head mix (4-wide): attn <- attn + relu(M @ attn) ----------------
__global__ __launch_bounds__(256) void mix_kernel(bf16* __restrict__ attnB,
                                                  const float* __restrict__ Mm){
  __shared__ float Ms[144];
  int t = threadIdx.x;
  if (t<144) Ms[t] = Mm[t];
  __syncthreads();
  size_t nm = ((size_t)blockIdx.x*256 + t)*4;
  unsigned short* base = (unsigned short*)attnB;
  float a[12][4];
  #pragma unroll
  for (int hh=0;hh<12;hh++){
    ushort4 u = *(const ushort4*)(base + (size_t)hh*1048576 + nm);
    a[hh][0]=u2f(u.x); a[hh][1]=u2f(u.y); a[hh][2]=u2f(u.z); a[hh][3]=u2f(u.w);
  }
  #pragma unroll
  for (int i=0;i<12;i++){
    float s0=0.f,s1=0.f,s2=0.f,s3=0.f;
    #pragma unroll
    for (int j=0;j<12;j++){
      float m = Ms[i*12+j];
      s0 += m*a[j][0]; s1 += m*a[j][1]; s2 += m*a[j][2]; s3 += m*a[j][3];
    }
    ushort4 o;
    o.x = f2bu(a[i][0] + fmaxf(s0,0.f));
    o.y = f2bu(a[i][1] + fmaxf(s1,0.f));
    o.z = f2bu(a[i][2] + fmaxf(s2,0.f));
    o.w = f2bu(a[i][3] + fmaxf(s3,0.f));
    *(ushort4*)(base + (size_t)i*1048576 + nm) = o;
  }
}

// ---------------- PV (MFMA) per h: comb[1024,1024] @ vt^T -> aout[n, h*64+d] bf16 ----------------
__global__ __launch_bounds__(256) void pv_gemm(const bf16* __restrict__ attnB,
                                               const bf16* __restrict__ vtB,
                                               bf16* __restrict__ aoutB){
  __shared__ bf16 As[128*32];
  int h = blockIdx.y; int m0 = blockIdx.x*128;
  const bf16* A  = attnB + (size_t)h*SEQ*1024;
  const bf16* Bv = vtB   + (size_t)h*DH*SEQ;
  int t = threadIdx.x, w = t>>6, lane = t&63;
  int ln16 = lane&15, q8 = (lane>>4)*8;
  f32x4 acc[2][4] = {};
  for (int k0=0; k0<1024; k0+=32){
    __syncthreads();
    #pragma unroll
    for (int i=0;i<2;i++){
      int cc = t + i*256;
      int r = cc>>2, ko = (cc&3)*8;
      *(short8*)&As[r*32+ko] = *(const short8*)&A[(size_t)(m0+r)*1024 + k0+ko];
    }
    __syncthreads();
    short8 bfr[4];
    #pragma unroll
    for (int ni=0;ni<4;ni++) bfr[ni] = *(const short8*)&Bv[(size_t)(ni*16+ln16)*SEQ + k0 + q8];
    short8 af[2];
    #pragma unroll
    for (int mi=0;mi<2;mi++) af[mi] = *(const short8*)&As[(w*32+mi*16+ln16)*32 + q8];
    #pragma unroll
    for (int mi=0;mi<2;mi++)
      #pragma unroll
      for (int ni=0;ni<4;ni++)
        acc[mi][ni] = __builtin_amdgcn_mfma_f32_16x16x32_bf16(af[mi], bfr[ni], acc[mi][ni], 0, 0, 0);
  }
  int quad4 = (lane>>4)*4;
  #pragma unroll
  for (int mi=0;mi<2;mi++)
    #pragma unroll
    for (int ni=0;ni<4;ni++)
      #pragma unroll
      for (int r=0;r<4;r++){
        int n = m0 + w*32 + mi*16 + quad4 + r;
        aoutB[(size_t)n*DMODEL + h*DH + ni*16 + ln16] = f2b(acc[mi][ni][r]);
      }
}

// ---------------- out proj (MFMA): aout[2048,768] @ w_out^T + b_out -> f32 ----------------
__global__ __launch_bounds__(256) void gemm_out(const bf16* __restrict__ A,
                                                const bf16* __restrict__ W,
                                                const float* __restrict__ bias,
                                                float* __restrict__ out){
  __shared__ bf16 As[128*32];
  __shared__ bf16 Bs[128*32];
  int n0 = blockIdx.x*128, m0 = blockIdx.y*128;
  int t = threadIdx.x, w = t>>6, lane = t&63;
  int ln16 = lane&15, q8 = (lane>>4)*8;
  int wm = w>>1, wn = w&1;
  f32x4 acc[4][4] = {};
  for (int k0=0; k0<768; k0+=32){
    __syncthreads();
    #pragma unroll
    for (int i=0;i<2;i++){
      int cc = t + i*256;
      int r = cc>>2, ko = (cc&3)*8;
      *(short8*)&As[r*32+ko] = *(const short8*)&A[(size_t)(m0+r)*768 + k0+ko];
      *(short8*)&Bs[r*32+ko] = *(const short8*)&W[(size_t)(n0+r)*768 + k0+ko];
    }
    __syncthreads();
    short8 af[4], bfr[4];
    #pragma unroll
    for (int mi=0;mi<4;mi++) af[mi]  = *(const short8*)&As[(wm*64+mi*16+ln16)*32 + q8];
    #pragma unroll
    for (int ni=0;ni<4;ni++) bfr[ni] = *(const short8*)&Bs[(wn*64+ni*16+ln16)*32 + q8];
    #pragma unroll
    for (int mi=0;mi<4;mi++)
      #pragma unroll
      for (int ni=0;ni<4;ni++)
        acc[mi][ni] = __builtin_amdgcn_mfma_f32_16x16x32_bf16(af[mi], bfr[ni], acc[mi][ni], 0, 0, 0);
  }
  int quad4 = (lane>>4)*4;
  #pragma unroll
  for (int mi=0;mi<4;mi++)
    #pragma unroll
    for (int ni=0;ni<4;ni++){
      int cg = n0 + wn*64 + ni*16 + ln16;
      #pragma unroll
      for (int r=0;r<4;r++){
        int m = m0 + wm*64 + mi*16 + quad4 + r;
        out[(size_t)m*768 + cg] = acc[mi][ni][r] + bias[cg];
      }
    }
}

extern "C" void kernel_launch(void* const* d_in, const int* in_sizes, int n_in,
                              void* d_out, int out_size, void* d_ws, size_t ws_size,
                              hipStream_t stream){
  const float* x     = (const float*)d_in[0];
  const float* ln_g  = (const float*)d_in[1];
  const float* ln_b  = (const float*)d_in[2];
  const float* w_qkv = (const float*)d_in[3];
  const float* w_out = (const float*)d_in[4];
  const float* b_out = (const float*)d_in[5];
  const float* theta = (const float*)d_in[6];
  const float* gnn   = (const float*)d_in[7];
  float* out = (float*)d_out;

  char* p = (char*)d_ws;
  bf16* xnb   = (bf16*)p; p += (size_t)2048*768*2;
  bf16* wqkvb = (bf16*)p; p += (size_t)2304*768*2;
  bf16* woutb = (bf16*)p; p += (size_t)768*768*2;
  bf16* qb    = (bf16*)p; p += (size_t)NB*NH*SEQ*DH*2;
  bf16* kb    = (bf16*)p; p += (size_t)NB*NH*SEQ*DH*2;
  bf16* vtb   = (bf16*)p; p += (size_t)NB*NH*SEQ*DH*2;
  bf16* aoutb = (bf16*)p; p += (size_t)2048*768*2;
  float* Mm   = (float*)p; p += 1024;
  bf16* attn  = (bf16*)p;                         // 12*1024*1024*2 = 25.2 MB (one batch)

  cvt_kernel<<<dim3((2304*768+255)/256), dim3(256), 0, stream>>>(w_qkv, wqkvb, 2304*768);
  cvt_kernel<<<dim3((768*768+255)/256),  dim3(256), 0, stream>>>(w_out, woutb, 768*768);
  ln_kernel<<<dim3(NB*SEQ), dim3(256), 0, stream>>>(x, ln_g, ln_b, xnb);
  mmat_kernel<<<dim3(1), dim3(256), 0, stream>>>(theta, gnn, Mm);
  gemm_qkv<<<dim3(18, 16), dim3(256), 0, stream>>>(xnb, wqkvb, qb, kb, vtb);

  for (int b=0; b<NB; b++){
    const bf16* qB = qb + (size_t)b*NH*SEQ*DH;
    const bf16* kB = kb + (size_t)b*NH*SEQ*DH;
    const bf16* vB = vtb + (size_t)b*NH*DH*SEQ;
    bf16* aoutB = aoutb + (size_t)b*SEQ*DMODEL;
    attn_kernel<<<dim3(64, NH), dim3(256), 0, stream>>>(qB, kB, attn);
    mix_kernel<<<dim3(1024), dim3(256), 0, stream>>>(attn, Mm);
    pv_gemm<<<dim3(8, NH), dim3(256), 0, stream>>>(attn, vB, aoutB);
  }

  gemm_out<<<dim3(6, 16), dim3(256), 0, stream>>>(aoutb, woutb, b_out, out);
}